// Round 3
// baseline (68.215 us; speedup 1.0000x reference)
//
#include <hip/hip_runtime.h>
#include <hip/hip_bf16.h>

#define NROWS 4096
#define DIM   1024
#define BT    128            // tile edge
#define BK    64             // K-step
#define NKT   (DIM / BK)     // 16 K-steps
#define NTB   (NROWS / BT)   // 32 tile-blocks per edge
#define TEMP_INV 10.0f

typedef __bf16 bf16x8 __attribute__((ext_vector_type(8)));
typedef float  f32x4  __attribute__((ext_vector_type(4)));

__device__ __forceinline__ void gload16(const void* g, void* l) {
    __builtin_amdgcn_global_load_lds(
        (const __attribute__((address_space(1))) void*)g,
        (__attribute__((address_space(3))) void*)l, 16, 0, 0);
}

__device__ __forceinline__ unsigned short f2bf(float f) {
    __hip_bfloat16 h = __float2bfloat16(f);
    return *reinterpret_cast<unsigned short*>(&h);
}

// Row-normalize fp32 -> bf16; also zeroes this row's partial buffers
// (replaces hipMemsetAsync — safe by stream ordering vs fused_gram).
__global__ __launch_bounds__(256) void normalize_k(const float* __restrict__ pred,
                                                   unsigned short* __restrict__ xn,
                                                   float* __restrict__ posw,
                                                   float* __restrict__ denw) {
    const int row = blockIdx.x;
    const int tid = threadIdx.x;
    const float4 v = reinterpret_cast<const float4*>(pred + (size_t)row * DIM)[tid];
    float ss = v.x * v.x + v.y * v.y + v.z * v.z + v.w * v.w;
    #pragma unroll
    for (int off = 32; off; off >>= 1) ss += __shfl_xor(ss, off, 64);
    __shared__ float red[4];
    if ((tid & 63) == 0) red[tid >> 6] = ss;
    __syncthreads();
    const float tot = red[0] + red[1] + red[2] + red[3];
    const float scale = 1.0f / fmaxf(sqrtf(tot), 1e-8f);
    ushort4 o;
    o.x = f2bf(v.x * scale);
    o.y = f2bf(v.y * scale);
    o.z = f2bf(v.z * scale);
    o.w = f2bf(v.w * scale);
    reinterpret_cast<ushort4*>(xn + (size_t)row * DIM)[tid] = o;
    if (tid == 0) { posw[row] = 0.0f; denw[row] = 0.0f; }
}

// Fused symmetric Gram-GEMM + contrastive epilogue over upper-triangular tiles.
// T3-minimum 2-phase: double-buffered LDS, stage(k+1) issued BEFORE compute(k),
// single __syncthreads per K-step (its implicit vmcnt drain lands after the
// MFMA phase has hidden the global-load latency).
__global__ __launch_bounds__(256, 2) void fused_gram(
        const unsigned short* __restrict__ xn, const int* __restrict__ tgt,
        float* __restrict__ posw, float* __restrict__ denw) {
    __shared__ unsigned short As[2][BT * BK];   // 2 x 16 KB
    __shared__ unsigned short Bs[2][BT * BK];   // 2 x 16 KB  (64 KB total)

    // Decode linear block id -> (bi, bj), bi <= bj.
    int bi = 0, rem = blockIdx.x;
    while (rem >= NTB - bi) { rem -= NTB - bi; ++bi; }
    const int bj = bi + rem;
    const bool diag = (bi == bj);
    const int rowbase = bi * BT;
    const int colbase = bj * BT;

    const int tid  = threadIdx.x;
    const int w    = tid >> 6;
    const int l    = tid & 63;
    const int wrow = w >> 1;
    const int wcol = w & 1;

    // Per-lane column indices / classes (one column per fj).
    int jc[4], tj[4];
    #pragma unroll
    for (int fj = 0; fj < 4; ++fj) {
        jc[fj] = colbase + wcol * 64 + fj * 16 + (l & 15);
        tj[fj] = tgt[jc[fj]];
    }

    f32x4 acc[4][4];
    #pragma unroll
    for (int i = 0; i < 4; ++i)
        #pragma unroll
        for (int j = 0; j < 4; ++j)
            acc[i][j] = (f32x4){0.f, 0.f, 0.f, 0.f};

    const int srow  = tid >> 3;        // 0..31
    const int skcol = (tid & 7) * 8;   // 0..56

    // Staging lambda-equivalent (macro keeps gload16 args literal).
#define STAGE(kt_, buf_)                                                        \
    do {                                                                        \
        const int k0_ = (kt_) * BK;                                             \
        _Pragma("unroll")                                                       \
        for (int c = 0; c < 4; ++c) {                                           \
            const int r = c * 32 + srow;                                        \
            gload16(xn + (size_t)(rowbase + r) * DIM + k0_ + skcol,             \
                    &As[buf_][c * 2048 + tid * 8]);                             \
            if (!diag)                                                          \
                gload16(xn + (size_t)(colbase + r) * DIM + k0_ + skcol,         \
                        &Bs[buf_][c * 2048 + tid * 8]);                         \
        }                                                                       \
    } while (0)

    STAGE(0, 0);
    __syncthreads();   // drain prologue stage

    int cur = 0;
    for (int kt = 0; kt < NKT; ++kt) {
        if (kt + 1 < NKT) STAGE(kt + 1, cur ^ 1);   // prefetch next (issued first)

        const unsigned short* as = As[cur];
        const unsigned short* bs = diag ? As[cur] : Bs[cur];
        #pragma unroll
        for (int ks = 0; ks < 2; ++ks) {
            bf16x8 a[4], b[4];
            #pragma unroll
            for (int fi = 0; fi < 4; ++fi)
                a[fi] = *reinterpret_cast<const bf16x8*>(
                    &as[(wrow * 64 + fi * 16 + (l & 15)) * BK + ks * 32 + (l >> 4) * 8]);
            #pragma unroll
            for (int fj = 0; fj < 4; ++fj)
                b[fj] = *reinterpret_cast<const bf16x8*>(
                    &bs[(wcol * 64 + fj * 16 + (l & 15)) * BK + ks * 32 + (l >> 4) * 8]);
            #pragma unroll
            for (int fi = 0; fi < 4; ++fi)
                #pragma unroll
                for (int fj = 0; fj < 4; ++fj)
                    acc[fi][fj] = __builtin_amdgcn_mfma_f32_16x16x32_bf16(
                        a[fi], b[fj], acc[fi][fj], 0, 0, 0);
        }
        __syncthreads();   // one barrier/step: drains prefetch, protects reuse
        cur ^= 1;
    }
#undef STAGE

    // Fused epilogue.  C/D layout: col = lane&15, row = (lane>>4)*4 + q  [m89/m91]
    float denc[4] = {0.f, 0.f, 0.f, 0.f};
    float posc[4] = {0.f, 0.f, 0.f, 0.f};

    #pragma unroll
    for (int fi = 0; fi < 4; ++fi) {
        const int ribase = rowbase + wrow * 64 + fi * 16 + (l >> 4) * 4;
        const int4 tiv = *reinterpret_cast<const int4*>(&tgt[ribase]);
        const int tia[4] = {tiv.x, tiv.y, tiv.z, tiv.w};
        float denr[4] = {0.f, 0.f, 0.f, 0.f};
        float posr[4] = {0.f, 0.f, 0.f, 0.f};
        #pragma unroll
        for (int q = 0; q < 4; ++q) {
            const int gi = ribase + q;
            const int ti = tia[q];
            #pragma unroll
            for (int fj = 0; fj < 4; ++fj) {
                const float s  = acc[fi][fj][q];
                const float pc = fmaxf(s, 1e-10f);
                const float e  = __expf(TEMP_INV * pc);
                if (ti != tj[fj]) {
                    denc[fj] += e;
                    denr[q]  += e;
                } else if (gi != jc[fj]) {
                    posc[fj] += pc;
                    posr[q]  += pc;
                }
            }
        }
        if (!diag) {
            // Row-side (mirror) reduction: lanes sharing a row differ in bits 0-3.
            #pragma unroll
            for (int q = 0; q < 4; ++q) {
                #pragma unroll
                for (int off = 1; off < 16; off <<= 1) {
                    denr[q] += __shfl_xor(denr[q], off, 64);
                    posr[q] += __shfl_xor(posr[q], off, 64);
                }
            }
            if ((l & 15) == 0) {
                #pragma unroll
                for (int q = 0; q < 4; ++q) {
                    atomicAdd(&denw[ribase + q], denr[q]);
                    atomicAdd(&posw[ribase + q], posr[q]);
                }
            }
        }
    }

    // Column-side reduction: lanes sharing a column differ in bits 4-5.
    #pragma unroll
    for (int fj = 0; fj < 4; ++fj) {
        #pragma unroll
        for (int off = 16; off < 64; off <<= 1) {
            denc[fj] += __shfl_xor(denc[fj], off, 64);
            posc[fj] += __shfl_xor(posc[fj], off, 64);
        }
        if (l < 16) {
            atomicAdd(&denw[jc[fj]], denc[fj]);
            atomicAdd(&posw[jc[fj]], posc[fj]);
        }
    }
}

// Single-block finalize: LDS class histogram + per-column loss + direct store.
__global__ __launch_bounds__(1024) void finalize_k(const float* __restrict__ posw,
                                                   const float* __restrict__ denw,
                                                   const int* __restrict__ tgt,
                                                   float* __restrict__ out) {
    __shared__ int hist[128];
    __shared__ float red[16];
    const int tid = threadIdx.x;
    if (tid < 128) hist[tid] = 0;
    __syncthreads();
    const int4 t4 = reinterpret_cast<const int4*>(tgt)[tid];   // 4 targets/thread
    atomicAdd(&hist[t4.x], 1);
    atomicAdd(&hist[t4.y], 1);
    atomicAdd(&hist[t4.z], 1);
    atomicAdd(&hist[t4.w], 1);
    __syncthreads();
    const int ta[4] = {t4.x, t4.y, t4.z, t4.w};
    float v = 0.0f;
    #pragma unroll
    for (int q = 0; q < 4; ++q) {
        const int j = tid * 4 + q;
        const float d = fmaxf(denw[j], 1e-10f);
        const float c = (float)(hist[ta[q]] - 1);
        v += TEMP_INV * posw[j] - c * __logf(d);
    }
    #pragma unroll
    for (int off = 32; off; off >>= 1) v += __shfl_xor(v, off, 64);
    if ((tid & 63) == 0) red[tid >> 6] = v;
    __syncthreads();
    if (tid == 0) {
        float s = 0.0f;
        #pragma unroll
        for (int i = 0; i < 16; ++i) s += red[i];
        out[0] = -s * (1.0f / 4096.0f);
    }
}

extern "C" void kernel_launch(void* const* d_in, const int* in_sizes, int n_in,
                              void* d_out, int out_size, void* d_ws, size_t ws_size,
                              hipStream_t stream) {
    const float* pred = (const float*)d_in[0];
    const int*   tgt  = (const int*)d_in[1];
    float* out = (float*)d_out;

    unsigned short* xn = (unsigned short*)d_ws;                      // 8 MB bf16
    float* posw = (float*)((char*)d_ws + (size_t)NROWS * DIM * 2);
    float* denw = posw + NROWS;

    normalize_k<<<NROWS, 256, 0, stream>>>(pred, xn, posw, denw);

    const int nblocks = NTB * (NTB + 1) / 2;   // 528 upper-triangular tiles
    fused_gram<<<nblocks, 256, 0, stream>>>(xn, tgt, posw, denw);

    finalize_k<<<1, 1024, 0, stream>>>(posw, denw, tgt, out);
}

// Round 4
// 50.160 us; speedup vs baseline: 1.3600x; 1.3600x over previous
//
#include <hip/hip_runtime.h>
#include <hip/hip_bf16.h>

#define NROWS 4096
#define DIM   1024
#define BT    256            // tile edge (256x256 per block)
#define BK    64             // K-step
#define NKT   (DIM / BK)     // 16 K-steps
#define NTB   (NROWS / BT)   // 16 tile-blocks per edge
#define TEMP_INV 10.0f

typedef __bf16 bf16x8 __attribute__((ext_vector_type(8)));
typedef float  f32x4  __attribute__((ext_vector_type(4)));

__device__ __forceinline__ void gload16(const void* g, void* l) {
    __builtin_amdgcn_global_load_lds(
        (const __attribute__((address_space(1))) void*)g,
        (__attribute__((address_space(3))) void*)l, 16, 0, 0);
}

__device__ __forceinline__ unsigned short f2bf(float f) {
    __hip_bfloat16 h = __float2bfloat16(f);
    return *reinterpret_cast<unsigned short*>(&h);
}

// Stage one 256x64 bf16 tile (32 KB) into LDS, 4 x gload16 per thread.
// LDS dest is LINEAR (wave-uniform base + lane*16B, required by m104); the
// st-style swizzle (granule ^= row&7, row = 128B) is applied by PRE-SWIZZLING
// the global source granule (rule 21: source permutation == read permutation).
__device__ __forceinline__ void stage_tile(const unsigned short* __restrict__ src,
                                           unsigned short* lds, int tid) {
    #pragma unroll
    for (int c = 0; c < 4; ++c) {
        const int p  = c * 512 + tid;        // LDS granule (16B units), linear
        const int r  = p >> 3;               // tile row (8 granules = 128B/row)
        const int kg = (p & 7) ^ (r & 7);    // logical k-granule held at p
        gload16(src + (size_t)r * DIM + kg * 8, lds + p * 8);
    }
}

// Row-normalize fp32 -> bf16; zeroes this row's partial accumulators.
__global__ __launch_bounds__(256) void normalize_k(const float* __restrict__ pred,
                                                   unsigned short* __restrict__ xn,
                                                   float* __restrict__ posw,
                                                   float* __restrict__ denw) {
    const int row = blockIdx.x;
    const int tid = threadIdx.x;
    const float4 v = reinterpret_cast<const float4*>(pred + (size_t)row * DIM)[tid];
    float ss = v.x * v.x + v.y * v.y + v.z * v.z + v.w * v.w;
    #pragma unroll
    for (int off = 32; off; off >>= 1) ss += __shfl_xor(ss, off, 64);
    __shared__ float red[4];
    if ((tid & 63) == 0) red[tid >> 6] = ss;
    __syncthreads();
    const float tot = red[0] + red[1] + red[2] + red[3];
    const float scale = 1.0f / fmaxf(sqrtf(tot), 1e-8f);
    ushort4 o;
    o.x = f2bf(v.x * scale);
    o.y = f2bf(v.y * scale);
    o.z = f2bf(v.z * scale);
    o.w = f2bf(v.w * scale);
    reinterpret_cast<ushort4*>(xn + (size_t)row * DIM)[tid] = o;
    if (tid == 0) { posw[row] = 0.0f; denw[row] = 0.0f; }
}

// Fused Gram-GEMM + contrastive epilogue.  Full 16x16 tile grid (256 blocks,
// 1/CU).  8 waves (2 row-groups x 4 col-groups), per-wave output 128x64.
// Counted-vmcnt software pipeline: stage(kt+1) issued before compute(kt),
// s_waitcnt vmcnt(8) (NOT 0) + raw s_barrier -> loads stay in flight a full
// iteration (~2.5K cyc of MFMA) before they're needed.
__global__ __launch_bounds__(512, 2) void fused_gram(
        const unsigned short* __restrict__ xn, const int* __restrict__ tgt,
        float* __restrict__ posw, float* __restrict__ denw) {
    __shared__ unsigned short As[2][BT * BK];   // 2 x 32 KB
    __shared__ unsigned short Bs[2][BT * BK];   // 2 x 32 KB  (128 KB total)

    const int bi = blockIdx.x >> 4;
    const int bj = blockIdx.x & 15;
    const int rowbase = bi * BT;
    const int colbase = bj * BT;

    const int tid = threadIdx.x;
    const int w   = tid >> 6;
    const int l   = tid & 63;
    const int wr  = w >> 2;      // 0..1  (row half: 128 rows)
    const int wc  = w & 3;       // 0..3  (col quarter: 64 cols)

    const unsigned short* arow = xn + (size_t)rowbase * DIM;
    const unsigned short* bcol = xn + (size_t)colbase * DIM;

    f32x4 acc[8][4];
    #pragma unroll
    for (int i = 0; i < 8; ++i)
        #pragma unroll
        for (int j = 0; j < 4; ++j)
            acc[i][j] = (f32x4){0.f, 0.f, 0.f, 0.f};

    // Prologue: stage K-tile 0 into slot 0.
    stage_tile(arow, &As[0][0], tid);
    stage_tile(bcol, &Bs[0][0], tid);

    for (int kt = 0; kt < NKT; ++kt) {
        const int cur = kt & 1;
        if (kt + 1 < NKT) {
            // Prefetch next K-tile into the other slot (8 loads/thread).
            stage_tile(arow + (kt + 1) * BK, &As[cur ^ 1][0], tid);
            stage_tile(bcol + (kt + 1) * BK, &Bs[cur ^ 1][0], tid);
            // Wait only for K-tile kt's 8 loads (issued one iteration ago).
            asm volatile("s_waitcnt vmcnt(8)" ::: "memory");
        } else {
            asm volatile("s_waitcnt vmcnt(0)" ::: "memory");
        }
        asm volatile("s_barrier" ::: "memory");   // all waves' slot-cur data landed

        const unsigned short* as = &As[cur][0];
        const unsigned short* bs = &Bs[cur][0];
        #pragma unroll
        for (int ks = 0; ks < 2; ++ks) {
            const int kg = ks * 4 + (l >> 4);     // logical k-granule 0..7
            bf16x8 a[8], b[4];
            #pragma unroll
            for (int fi = 0; fi < 8; ++fi) {
                const int lr = wr * 128 + fi * 16 + (l & 15);
                a[fi] = *reinterpret_cast<const bf16x8*>(
                    &as[lr * 64 + ((kg ^ (lr & 7)) * 8)]);
            }
            #pragma unroll
            for (int fj = 0; fj < 4; ++fj) {
                const int lr = wc * 64 + fj * 16 + (l & 15);
                b[fj] = *reinterpret_cast<const bf16x8*>(
                    &bs[lr * 64 + ((kg ^ (lr & 7)) * 8)]);
            }
            #pragma unroll
            for (int fi = 0; fi < 8; ++fi)
                #pragma unroll
                for (int fj = 0; fj < 4; ++fj)
                    acc[fi][fj] = __builtin_amdgcn_mfma_f32_16x16x32_bf16(
                        a[fi], b[fj], acc[fi][fj], 0, 0, 0);
        }
        // End barrier: all reads of slot cur done before iter kt+1 overwrites
        // the OTHER slot's predecessor... and before kt+2's stage hits cur.
        asm volatile("s_barrier" ::: "memory");
    }

    // Fused epilogue (column-side only: full grid covers both (i,j) and (j,i)).
    // C/D layout: col = lane&15, row = (lane>>4)*4 + q  [m89/m91, verified R1]
    int jc[4], tj[4];
    #pragma unroll
    for (int fj = 0; fj < 4; ++fj) {
        jc[fj] = colbase + wc * 64 + fj * 16 + (l & 15);
        tj[fj] = tgt[jc[fj]];
    }
    float denc[4] = {0.f, 0.f, 0.f, 0.f};
    float posc[4] = {0.f, 0.f, 0.f, 0.f};

    #pragma unroll
    for (int fi = 0; fi < 8; ++fi) {
        const int ribase = rowbase + wr * 128 + fi * 16 + (l >> 4) * 4;
        const int4 tiv = *reinterpret_cast<const int4*>(&tgt[ribase]);
        const int tia[4] = {tiv.x, tiv.y, tiv.z, tiv.w};
        #pragma unroll
        for (int q = 0; q < 4; ++q) {
            const int gi = ribase + q;
            const int ti = tia[q];
            #pragma unroll
            for (int fj = 0; fj < 4; ++fj) {
                const float s  = acc[fi][fj][q];
                const float pc = fmaxf(s, 1e-10f);
                const float e  = __expf(TEMP_INV * pc);
                if (ti != tj[fj]) {
                    denc[fj] += e;
                } else if (gi != jc[fj]) {
                    posc[fj] += pc;
                }
            }
        }
    }

    // Lanes sharing a column differ in bits 4-5.
    #pragma unroll
    for (int fj = 0; fj < 4; ++fj) {
        #pragma unroll
        for (int off = 16; off < 64; off <<= 1) {
            denc[fj] += __shfl_xor(denc[fj], off, 64);
            posc[fj] += __shfl_xor(posc[fj], off, 64);
        }
        if (l < 16) {
            atomicAdd(&denw[jc[fj]], denc[fj]);
            atomicAdd(&posw[jc[fj]], posc[fj]);
        }
    }
}

// Single-block finalize: LDS class histogram + per-column loss + direct store.
__global__ __launch_bounds__(1024) void finalize_k(const float* __restrict__ posw,
                                                   const float* __restrict__ denw,
                                                   const int* __restrict__ tgt,
                                                   float* __restrict__ out) {
    __shared__ int hist[128];
    __shared__ float red[16];
    const int tid = threadIdx.x;
    if (tid < 128) hist[tid] = 0;
    __syncthreads();
    const int4 t4 = reinterpret_cast<const int4*>(tgt)[tid];   // 4 targets/thread
    atomicAdd(&hist[t4.x], 1);
    atomicAdd(&hist[t4.y], 1);
    atomicAdd(&hist[t4.z], 1);
    atomicAdd(&hist[t4.w], 1);
    __syncthreads();
    const int ta[4] = {t4.x, t4.y, t4.z, t4.w};
    float v = 0.0f;
    #pragma unroll
    for (int q = 0; q < 4; ++q) {
        const int j = tid * 4 + q;
        const float d = fmaxf(denw[j], 1e-10f);
        const float c = (float)(hist[ta[q]] - 1);
        v += TEMP_INV * posw[j] - c * __logf(d);
    }
    #pragma unroll
    for (int off = 32; off; off >>= 1) v += __shfl_xor(v, off, 64);
    if ((tid & 63) == 0) red[tid >> 6] = v;
    __syncthreads();
    if (tid == 0) {
        float s = 0.0f;
        #pragma unroll
        for (int i = 0; i < 16; ++i) s += red[i];
        out[0] = -s * (1.0f / 4096.0f);
    }
}

extern "C" void kernel_launch(void* const* d_in, const int* in_sizes, int n_in,
                              void* d_out, int out_size, void* d_ws, size_t ws_size,
                              hipStream_t stream) {
    const float* pred = (const float*)d_in[0];
    const int*   tgt  = (const int*)d_in[1];
    float* out = (float*)d_out;

    unsigned short* xn = (unsigned short*)d_ws;                      // 8 MB bf16
    float* posw = (float*)((char*)d_ws + (size_t)NROWS * DIM * 2);
    float* denw = posw + NROWS;

    normalize_k<<<NROWS, 256, 0, stream>>>(pred, xn, posw, denw);

    fused_gram<<<NTB * NTB, 512, 0, stream>>>(xn, tgt, posw, denw);  // 256 blocks

    finalize_k<<<1, 1024, 0, stream>>>(posw, denw, tgt, out);
}

// Round 5
// 49.047 us; speedup vs baseline: 1.3908x; 1.0227x over previous
//
#include <hip/hip_runtime.h>
#include <hip/hip_bf16.h>

#define NROWS 4096
#define DIM   1024
#define BT    256            // tile edge (256x256 per block)
#define BK    32             // K-step
#define NKT   (DIM / BK)     // 32 K-steps
#define NTB   (NROWS / BT)   // 16 tile-blocks per edge
#define TEMP_INV 10.0f

typedef __bf16 bf16x8 __attribute__((ext_vector_type(8)));
typedef float  f32x4  __attribute__((ext_vector_type(4)));

__device__ __forceinline__ void gload16(const void* g, void* l) {
    __builtin_amdgcn_global_load_lds(
        (const __attribute__((address_space(1))) void*)g,
        (__attribute__((address_space(3))) void*)l, 16, 0, 0);
}

__device__ __forceinline__ unsigned short f2bf(float f) {
    __hip_bfloat16 h = __float2bfloat16(f);
    return *reinterpret_cast<unsigned short*>(&h);
}

// Stage one 256x32 bf16 tile (16 KB) into LDS: 2 gload16/thread.
// Linear LDS dest (m104); bank-swizzle kg ^= (r>>1)&3 applied by pre-swizzling
// the global source granule (rule 21: source perm == read perm, involution).
// Rows are 64 B (4 granules); swizzle spreads 16-row column reads 2-way (free).
__device__ __forceinline__ void stage_tile32(const unsigned short* __restrict__ src,
                                             unsigned short* lds, int tid) {
    #pragma unroll
    for (int c = 0; c < 2; ++c) {
        const int p  = c * 512 + tid;            // physical granule 0..1023
        const int r  = p >> 2;                   // tile row 0..255
        const int kg = (p & 3) ^ ((r >> 1) & 3); // logical k-granule at p
        gload16(src + (size_t)r * DIM + kg * 8, lds + p * 8);
    }
}

// Row-normalize fp32 -> bf16; zeroes this row's partial accumulators.
__global__ __launch_bounds__(256) void normalize_k(const float* __restrict__ pred,
                                                   unsigned short* __restrict__ xn,
                                                   float* __restrict__ posw,
                                                   float* __restrict__ denw) {
    const int row = blockIdx.x;
    const int tid = threadIdx.x;
    const float4 v = reinterpret_cast<const float4*>(pred + (size_t)row * DIM)[tid];
    float ss = v.x * v.x + v.y * v.y + v.z * v.z + v.w * v.w;
    #pragma unroll
    for (int off = 32; off; off >>= 1) ss += __shfl_xor(ss, off, 64);
    __shared__ float red[4];
    if ((tid & 63) == 0) red[tid >> 6] = ss;
    __syncthreads();
    const float tot = red[0] + red[1] + red[2] + red[3];
    const float scale = 1.0f / fmaxf(sqrtf(tot), 1e-8f);
    ushort4 o;
    o.x = f2bf(v.x * scale);
    o.y = f2bf(v.y * scale);
    o.z = f2bf(v.z * scale);
    o.w = f2bf(v.w * scale);
    reinterpret_cast<ushort4*>(xn + (size_t)row * DIM)[tid] = o;
    if (tid == 0) { posw[row] = 0.0f; denw[row] = 0.0f; }
}

// Fused Gram-GEMM + contrastive epilogue.  Full 16x16 grid (256 blocks, 1/CU),
// 8 waves (2M x 4N), per-wave output 128x64.
// Deep pipeline: 4 LDS slots, stage(kt+3) during kt, vmcnt(8) at top (tiles
// kt+1,kt+2 stay in flight).  2 sub-phases per K-step (fi-halves, 16 MFMA each)
// with setprio + mid-barrier -> wave role-split so LDS and MFMA pipes co-run.
// Slot safety: slot (kt+3)&3's old content (tile kt-1) was consumed in step
// kt-1, whose reads retire before its consuming MFMAs, which precede the top
// barrier of kt that every wave passes before issuing kt+3's stage.
__global__ __launch_bounds__(512, 2) void fused_gram(
        const unsigned short* __restrict__ xn, const int* __restrict__ tgt,
        float* __restrict__ posw, float* __restrict__ denw) {
    __shared__ unsigned short As[4][BT * BK];   // 4 x 16 KB
    __shared__ unsigned short Bs[4][BT * BK];   // 4 x 16 KB  (128 KB total)

    const int bi = blockIdx.x >> 4;
    const int bj = blockIdx.x & 15;
    const int rowbase = bi * BT;
    const int colbase = bj * BT;

    const int tid = threadIdx.x;
    const int w   = tid >> 6;
    const int l   = tid & 63;
    const int wr  = w >> 2;      // 0..1  (row half: 128 rows)
    const int wc  = w & 3;       // 0..3  (col quarter: 64 cols)
    const int l15 = l & 15;
    const int kgl = l >> 4;      // logical k-granule 0..3

    const unsigned short* arow = xn + (size_t)rowbase * DIM;
    const unsigned short* bcol = xn + (size_t)colbase * DIM;

    // Hoisted LDS element offsets (swizzled) for fragment reads.
    int ga[8], gb[4];
    #pragma unroll
    for (int fi = 0; fi < 8; ++fi) {
        const int lr = wr * 128 + fi * 16 + l15;
        ga[fi] = (lr * 4 + (kgl ^ ((lr >> 1) & 3))) * 8;
    }
    #pragma unroll
    for (int fj = 0; fj < 4; ++fj) {
        const int lr = wc * 64 + fj * 16 + l15;
        gb[fj] = (lr * 4 + (kgl ^ ((lr >> 1) & 3))) * 8;
    }

    f32x4 acc[8][4];
    #pragma unroll
    for (int i = 0; i < 8; ++i)
        #pragma unroll
        for (int j = 0; j < 4; ++j)
            acc[i][j] = (f32x4){0.f, 0.f, 0.f, 0.f};

    // Prologue: stage tiles 0,1,2 (12 gload_lds per thread-pair group).
    stage_tile32(arow,          &As[0][0], tid);
    stage_tile32(bcol,          &Bs[0][0], tid);
    stage_tile32(arow + BK,     &As[1][0], tid);
    stage_tile32(bcol + BK,     &Bs[1][0], tid);
    stage_tile32(arow + 2 * BK, &As[2][0], tid);
    stage_tile32(bcol + 2 * BK, &Bs[2][0], tid);

    for (int kt = 0; kt < NKT; ++kt) {
        const int cur = kt & 3;
        // Wait for tile kt only; keep tiles kt+1, kt+2 (8 loads/wave) in flight.
        if (kt < NKT - 2)       asm volatile("s_waitcnt vmcnt(8)" ::: "memory");
        else if (kt == NKT - 2) asm volatile("s_waitcnt vmcnt(4)" ::: "memory");
        else                    asm volatile("s_waitcnt vmcnt(0)" ::: "memory");
        asm volatile("s_barrier" ::: "memory");   // all waves' slot-kt data landed

        const unsigned short* as = &As[cur][0];
        const unsigned short* bs = &Bs[cur][0];
        bf16x8 a[8], b[4];

        // ---- Phase A: fi 0-3 ----
        #pragma unroll
        for (int fi = 0; fi < 4; ++fi)
            a[fi] = *reinterpret_cast<const bf16x8*>(&as[ga[fi]]);
        #pragma unroll
        for (int fj = 0; fj < 4; ++fj)
            b[fj] = *reinterpret_cast<const bf16x8*>(&bs[gb[fj]]);
        if (kt + 3 < NKT)
            stage_tile32(arow + (kt + 3) * BK, &As[(kt + 3) & 3][0], tid);
        __builtin_amdgcn_s_setprio(1);
        #pragma unroll
        for (int fi = 0; fi < 4; ++fi)
            #pragma unroll
            for (int fj = 0; fj < 4; ++fj)
                acc[fi][fj] = __builtin_amdgcn_mfma_f32_16x16x32_bf16(
                    a[fi], b[fj], acc[fi][fj], 0, 0, 0);
        __builtin_amdgcn_s_setprio(0);
        asm volatile("s_barrier" ::: "memory");   // phase boundary (role stagger)

        // ---- Phase B: fi 4-7 (reuse b) ----
        #pragma unroll
        for (int fi = 4; fi < 8; ++fi)
            a[fi] = *reinterpret_cast<const bf16x8*>(&as[ga[fi]]);
        if (kt + 3 < NKT)
            stage_tile32(bcol + (kt + 3) * BK, &Bs[(kt + 3) & 3][0], tid);
        __builtin_amdgcn_s_setprio(1);
        #pragma unroll
        for (int fi = 4; fi < 8; ++fi)
            #pragma unroll
            for (int fj = 0; fj < 4; ++fj)
                acc[fi][fj] = __builtin_amdgcn_mfma_f32_16x16x32_bf16(
                    a[fi], b[fj], acc[fi][fj], 0, 0, 0);
        __builtin_amdgcn_s_setprio(0);
        // End barrier merged with next iteration's top vmcnt+barrier.
    }

    // Fused epilogue (column-side only; full grid covers both (i,j),(j,i)).
    // C/D layout: col = lane&15, row = (lane>>4)*4 + q  [m89/m91, verified]
    int jc[4], tj[4];
    #pragma unroll
    for (int fj = 0; fj < 4; ++fj) {
        jc[fj] = colbase + wc * 64 + fj * 16 + l15;
        tj[fj] = tgt[jc[fj]];
    }
    float denc[4] = {0.f, 0.f, 0.f, 0.f};
    float posc[4] = {0.f, 0.f, 0.f, 0.f};

    #pragma unroll
    for (int fi = 0; fi < 8; ++fi) {
        const int ribase = rowbase + wr * 128 + fi * 16 + (l >> 4) * 4;
        const int4 tiv = *reinterpret_cast<const int4*>(&tgt[ribase]);
        const int tia[4] = {tiv.x, tiv.y, tiv.z, tiv.w};
        #pragma unroll
        for (int q = 0; q < 4; ++q) {
            const int gi = ribase + q;
            const int ti = tia[q];
            #pragma unroll
            for (int fj = 0; fj < 4; ++fj) {
                const float s  = acc[fi][fj][q];
                const float pc = fmaxf(s, 1e-10f);
                const float e  = __expf(TEMP_INV * pc);
                if (ti != tj[fj]) {
                    denc[fj] += e;
                } else if (gi != jc[fj]) {
                    posc[fj] += pc;
                }
            }
        }
    }

    // Lanes sharing a column differ in bits 4-5.
    #pragma unroll
    for (int fj = 0; fj < 4; ++fj) {
        #pragma unroll
        for (int off = 16; off < 64; off <<= 1) {
            denc[fj] += __shfl_xor(denc[fj], off, 64);
            posc[fj] += __shfl_xor(posc[fj], off, 64);
        }
        if (l < 16) {
            atomicAdd(&denw[jc[fj]], denc[fj]);
            atomicAdd(&posw[jc[fj]], posc[fj]);
        }
    }
}

// Single-block finalize: LDS class histogram + per-column loss + direct store.
__global__ __launch_bounds__(1024) void finalize_k(const float* __restrict__ posw,
                                                   const float* __restrict__ denw,
                                                   const int* __restrict__ tgt,
                                                   float* __restrict__ out) {
    __shared__ int hist[128];
    __shared__ float red[16];
    const int tid = threadIdx.x;
    if (tid < 128) hist[tid] = 0;
    __syncthreads();
    const int4 t4 = reinterpret_cast<const int4*>(tgt)[tid];   // 4 targets/thread
    atomicAdd(&hist[t4.x], 1);
    atomicAdd(&hist[t4.y], 1);
    atomicAdd(&hist[t4.z], 1);
    atomicAdd(&hist[t4.w], 1);
    __syncthreads();
    const int ta[4] = {t4.x, t4.y, t4.z, t4.w};
    float v = 0.0f;
    #pragma unroll
    for (int q = 0; q < 4; ++q) {
        const int j = tid * 4 + q;
        const float d = fmaxf(denw[j], 1e-10f);
        const float c = (float)(hist[ta[q]] - 1);
        v += TEMP_INV * posw[j] - c * __logf(d);
    }
    #pragma unroll
    for (int off = 32; off; off >>= 1) v += __shfl_xor(v, off, 64);
    if ((tid & 63) == 0) red[tid >> 6] = v;
    __syncthreads();
    if (tid == 0) {
        float s = 0.0f;
        #pragma unroll
        for (int i = 0; i < 16; ++i) s += red[i];
        out[0] = -s * (1.0f / 4096.0f);
    }
}

extern "C" void kernel_launch(void* const* d_in, const int* in_sizes, int n_in,
                              void* d_out, int out_size, void* d_ws, size_t ws_size,
                              hipStream_t stream) {
    const float* pred = (const float*)d_in[0];
    const int*   tgt  = (const int*)d_in[1];
    float* out = (float*)d_out;

    unsigned short* xn = (unsigned short*)d_ws;                      // 8 MB bf16
    float* posw = (float*)((char*)d_ws + (size_t)NROWS * DIM * 2);
    float* denw = posw + NROWS;

    normalize_k<<<NROWS, 256, 0, stream>>>(pred, xn, posw, denw);

    fused_gram<<<NTB * NTB, 512, 0, stream>>>(xn, tgt, posw, denw);  // 256 blocks

    finalize_k<<<1, 1024, 0, stream>>>(posw, denw, tgt, out);
}